// Round 5
// baseline (1392.003 us; speedup 1.0000x reference)
//
#include <hip/hip_runtime.h>

// MLA shapes (fixed)
#define B_ 4
#define S_ 1024
#define H_ 4096
#define NH_ 32
#define QHD_ 192
#define EPS_ 1e-6f

typedef __bf16 bf16x8 __attribute__((ext_vector_type(8)));
typedef float floatx4 __attribute__((ext_vector_type(4)));

__device__ __forceinline__ unsigned short f2bf(float f) {
  unsigned int u = __builtin_bit_cast(unsigned int, f);
  u += 0x7fffu + ((u >> 16) & 1u);   // round-to-nearest-even (finite data only)
  return (unsigned short)(u >> 16);
}
__device__ __forceinline__ float bf2f(unsigned short s) {
  return __builtin_bit_cast(float, ((unsigned int)s) << 16);
}

// async global->LDS, 16B per lane; LDS dest = wave-uniform base + lane*16 (m104)
__device__ __forceinline__ void gload16(const unsigned short* g, unsigned short* l) {
  __builtin_amdgcn_global_load_lds(
      (const __attribute__((address_space(1))) void*)g,
      (__attribute__((address_space(3))) void*)l, 16, 0, 0);
}

// DPP row_ror cross-lane (VALU pipe, per-16-lane row = our lm groups).
template<int C>
__device__ __forceinline__ float dpp_ror(float v) {
  return __builtin_bit_cast(float,
      __builtin_amdgcn_mov_dpp(__builtin_bit_cast(int, v), 0x120 | C, 0xf, 0xf, false));
}
__device__ __forceinline__ float rmax16(float v) {   // allreduce max over 16-lane row
  v = fmaxf(v, dpp_ror<1>(v));
  v = fmaxf(v, dpp_ror<2>(v));
  v = fmaxf(v, dpp_ror<4>(v));
  v = fmaxf(v, dpp_ror<8>(v));
  return v;
}
__device__ __forceinline__ float rsum16(float v) {   // allreduce sum over 16-lane row
  v += dpp_ror<1>(v);
  v += dpp_ror<2>(v);
  v += dpp_ror<4>(v);
  v += dpp_ror<8>(v);
  return v;
}

// ---------------------------------------------------------------------------
// fp32 -> bf16 convert (hs), 8 elems/thread
// ---------------------------------------------------------------------------
__global__ __launch_bounds__(256) void convert_kernel(
    const float* __restrict__ x, unsigned short* __restrict__ y)
{
  const int i = (blockIdx.x * 256 + threadIdx.x) * 8;
  const float4 a = *(const float4*)(x + i);
  const float4 b = *(const float4*)(x + i + 4);
  ushort4 u, v;
  u.x = f2bf(a.x); u.y = f2bf(a.y); u.z = f2bf(a.z); u.w = f2bf(a.w);
  v.x = f2bf(b.x); v.y = f2bf(b.y); v.z = f2bf(b.z); v.w = f2bf(b.w);
  *(ushort4*)(y + i) = u;
  *(ushort4*)(y + i + 4) = v;
}

// ---------------------------------------------------------------------------
// W (KxN fp32 row-major) -> Wt (NxK bf16 row-major). 32x32 LDS tiles.
// ---------------------------------------------------------------------------
__global__ __launch_bounds__(256) void transpose_kernel(
    const float* __restrict__ W, unsigned short* __restrict__ Wt,
    const int K, const int N)
{
  __shared__ float tile[32][33];
  const int tx = threadIdx.x & 31, ty = threadIdx.x >> 5;
  const int nb = blockIdx.x << 5, kb = blockIdx.y << 5;
#pragma unroll
  for (int j = 0; j < 4; ++j)
    tile[ty + j * 8][tx] = W[(size_t)(kb + ty + j * 8) * N + nb + tx];
  __syncthreads();
#pragma unroll
  for (int j = 0; j < 4; ++j)
    Wt[(size_t)(nb + ty + j * 8) * K + kb + tx] = f2bf(tile[tx][ty + j * 8]);
}

// ---------------------------------------------------------------------------
// m97-class GEMM: C(MxN) = A(MxK) @ Bt(NxK)^T, both bf16, staged via
// global_load_lds width=16 into unpadded LDS [128][32]. 128x128 tile, BK=32,
// 4 waves (2x2 of 64x64), mfma_f32_16x16x32_bf16.
// OMODE: 0 = fp32 row-major; 1 = bf16 row-major; 2 = bf16 (B,NH,S,256) kv;
//        3 = split fp32: col<1536 -> Cv (ldc 1536), else Cv2 (ldc 576).
// M%128==0, K%32==0; Bt rows padded to 128-mult (pad contents finite poison).
// ---------------------------------------------------------------------------
template<int OMODE>
__global__ __launch_bounds__(256, 2) void gemm_bt(
    const unsigned short* __restrict__ A, const unsigned short* __restrict__ Bt,
    void* __restrict__ Cv, void* __restrict__ Cv2, const int N, const int K,
    const int lda, const int ldb, const int ldc)
{
  __shared__ unsigned short As[128 * 32];
  __shared__ unsigned short Bs[128 * 32];

  const int t = threadIdx.x;
  const int m0 = blockIdx.x * 128, n0 = blockIdx.y * 128;
  const int w = t >> 6, lane = t & 63;
  const int wm = (w >> 1) << 6, wn = (w & 1) << 6;
  const int lm = lane & 15, lq = lane >> 4;

  const floatx4 vzero = {0.f, 0.f, 0.f, 0.f};
  floatx4 acc[4][4];
#pragma unroll
  for (int i = 0; i < 4; ++i)
#pragma unroll
    for (int j = 0; j < 4; ++j) acc[i][j] = vzero;

  // staging: wave w does calls i=0,1; call covers 16 rows x 32 cols (1 KB).
  const int srow = (w << 5) + (lane >> 2);
  const int skc = (lane & 3) << 3;
  const unsigned short* gA = A + (size_t)(m0 + srow) * lda + skc;
  const unsigned short* gB = Bt + (size_t)(n0 + srow) * ldb + skc;
  unsigned short* lA0 = &As[(w << 1) * 512];
  unsigned short* lA1 = &As[((w << 1) + 1) * 512];
  unsigned short* lB0 = &Bs[(w << 1) * 512];
  unsigned short* lB1 = &Bs[((w << 1) + 1) * 512];

  const int nk = K >> 5;
  for (int kb = 0; kb < nk; ++kb) {
    const int k0 = kb << 5;
    __syncthreads();
    gload16(gA + k0, lA0);
    gload16(gA + (size_t)16 * lda + k0, lA1);
    gload16(gB + k0, lB0);
    gload16(gB + (size_t)16 * ldb + k0, lB1);
    __syncthreads();

    bf16x8 af[4], bfr[4];
#pragma unroll
    for (int mi = 0; mi < 4; ++mi)
      af[mi] = *(const bf16x8*)&As[(wm + mi * 16 + lm) * 32 + (lq << 3)];
#pragma unroll
    for (int ni = 0; ni < 4; ++ni)
      bfr[ni] = *(const bf16x8*)&Bs[(wn + ni * 16 + lm) * 32 + (lq << 3)];
#pragma unroll
    for (int mi = 0; mi < 4; ++mi)
#pragma unroll
      for (int ni = 0; ni < 4; ++ni)
        acc[mi][ni] = __builtin_amdgcn_mfma_f32_16x16x32_bf16(af[mi], bfr[ni], acc[mi][ni], 0, 0, 0);
  }

#pragma unroll
  for (int mi = 0; mi < 4; ++mi) {
    const int row = m0 + wm + mi * 16 + (lq << 2);
#pragma unroll
    for (int ni = 0; ni < 4; ++ni) {
      const int col = n0 + wn + ni * 16 + lm;
      if (col < N) {
#pragma unroll
        for (int r = 0; r < 4; ++r) {
          if constexpr (OMODE == 0)
            ((float*)Cv)[(size_t)(row + r) * ldc + col] = acc[mi][ni][r];
          else if constexpr (OMODE == 1)
            ((unsigned short*)Cv)[(size_t)(row + r) * ldc + col] = f2bf(acc[mi][ni][r]);
          else if constexpr (OMODE == 2) {
            const int rr2 = row + r;  // (B,NH,S,256): h=col>>8, d=col&255
            ((unsigned short*)Cv)[(((size_t)(rr2 >> 10) * NH_ + (col >> 8)) * S_ + (rr2 & 1023)) * 256 + (col & 255)] = f2bf(acc[mi][ni][r]);
          } else {  // OMODE == 3: q_a (cols 0..1535) | ckv (cols 1536..2111)
            if (col < 1536)
              ((float*)Cv)[(size_t)(row + r) * 1536 + col] = acc[mi][ni][r];
            else
              ((float*)Cv2)[(size_t)(row + r) * 576 + (col - 1536)] = acc[mi][ni][r];
          }
        }
      }
    }
  }
}

// ---------------------------------------------------------------------------
// LayerNorm: x fp32 rows (len L, stride xstride) -> y bf16 (stride ystride).
// ---------------------------------------------------------------------------
__global__ __launch_bounds__(256) void ln_kernel(
    const float* __restrict__ x, const float* __restrict__ g,
    const float* __restrict__ bias, unsigned short* __restrict__ y,
    const int L, const int xstride, const int ystride)
{
  __shared__ float sh[4];
  const int t = threadIdx.x;
  const float* xr = x + (size_t)blockIdx.x * xstride;
  unsigned short* yr = y + (size_t)blockIdx.x * ystride;
  const int n = L >> 8;
  float vals[6];
  float s = 0.f;
  for (int i = 0; i < n; ++i) { vals[i] = xr[t + (i << 8)]; s += vals[i]; }
#pragma unroll
  for (int off = 32; off; off >>= 1) s += __shfl_down(s, off);
  if ((t & 63) == 0) sh[t >> 6] = s;
  __syncthreads();
  const float mean = (sh[0] + sh[1] + sh[2] + sh[3]) / (float)L;
  float vs = 0.f;
  for (int i = 0; i < n; ++i) { const float d = vals[i] - mean; vs += d * d; }
#pragma unroll
  for (int off = 32; off; off >>= 1) vs += __shfl_down(vs, off);
  __syncthreads();
  if ((t & 63) == 0) sh[t >> 6] = vs;
  __syncthreads();
  const float inv = rsqrtf((sh[0] + sh[1] + sh[2] + sh[3]) / (float)L + EPS_);
  for (int i = 0; i < n; ++i) {
    const int c = t + (i << 8);
    yr[c] = f2bf((vals[i] - mean) * inv * g[c] + bias[c]);
  }
}

// ---------------------------------------------------------------------------
// RoPE on q_pe (cols 128..191 of each 192-wide head), in place on bf16 q.
// ---------------------------------------------------------------------------
__global__ __launch_bounds__(256) void rope_q_kernel(
    unsigned short* __restrict__ q, const float* __restrict__ cosp,
    const float* __restrict__ sinp, const int* __restrict__ pos)
{
  const int i = blockIdx.x * 256 + threadIdx.x;  // B*S*NH*32
  const int p = i & 31;
  const int h = (i >> 5) & 31;
  const int bs = i >> 10;
  const int pid = pos[bs];
  const size_t base = ((size_t)bs * NH_ + h) * QHD_ + 128;
  const float x1 = bf2f(q[base + p]);
  const float x2 = bf2f(q[base + p + 32]);
  const float* cr = cosp + (size_t)pid * 64;
  const float* sr = sinp + (size_t)pid * 64;
  q[base + p]      = f2bf(x1 * cr[p] - x2 * sr[p]);
  q[base + p + 32] = f2bf(x2 * cr[p + 32] + x1 * sr[p + 32]);
}

// RoPE on k_pe: ckv cols 512..575 (fp32) -> kpe bf16 (B,S,64)
__global__ __launch_bounds__(256) void rope_k_kernel(
    const float* __restrict__ ckv, const float* __restrict__ cosp,
    const float* __restrict__ sinp, const int* __restrict__ pos,
    unsigned short* __restrict__ kpe)
{
  const int i = blockIdx.x * 256 + threadIdx.x;  // B*S*32
  const int p = i & 31;
  const int bs = i >> 5;
  const int pid = pos[bs];
  const float* row = ckv + (size_t)bs * 576 + 512;
  const float x1 = row[p], x2 = row[p + 32];
  const float* cr = cosp + (size_t)pid * 64;
  const float* sr = sinp + (size_t)pid * 64;
  kpe[(size_t)bs * 64 + p]      = f2bf(x1 * cr[p] - x2 * sr[p]);
  kpe[(size_t)bs * 64 + p + 32] = f2bf(x2 * cr[p + 32] + x1 * sr[p + 32]);
}

// ---------------------------------------------------------------------------
// MFMA flash attention. Block = 8 waves = (b,h,128 q). Round-5 changes:
//  (a) DPP row_ror rotate-reduce (VALU) replaces __shfl_xor (ds_swizzle, LDS
//      pipe) for the 16-lane softmax max/sum allreduces: shorter serial
//      chains AND frees the LDS pipe (32 ds ops/thread/tile removed).
//  (b) T13 defer-max (THR=6 base-2, P<=64): skip the exp2+rescale of o/lrow
//      when no lane's tile-max exceeds the running max by >6 — removes the
//      accumulator-chain dependency on the common path.
//  (c) Ps stride 72->68: u16 P-stores were 4-way bank-conflicted
//      (lq*144 === 16 mod 32); stride 68 gives banks lq*8+lm/2 (free).
//  (d) s_setprio(1) around MFMA clusters (T5; +4-7% attn per m191).
//  (e) carried: 512-thr/128-q blocks, named-reg T14 prefetch, static-index
//      compute, Vt XOR-swizzle, base-2 softmax.
// ---------------------------------------------------------------------------
__global__ __launch_bounds__(512, 4) void attn_kernel(
    const unsigned short* __restrict__ qb, const unsigned short* __restrict__ kvb,
    const unsigned short* __restrict__ kpe, unsigned short* __restrict__ o)
{
  __shared__ unsigned short Ks[64 * 200];      // [k][d 0..191], stride 200
  __shared__ unsigned short Vt[128 * 72];      // [vd][k], stride 72, swizzled cols
  __shared__ unsigned short Ps[8 * 16 * 68];   // per-wave [m][k], stride 68

  const int t = threadIdx.x;
  const int q0 = (int)gridDim.x - 1 - (int)blockIdx.x;  // longest first
  const int h = blockIdx.y, b = blockIdx.z;
  const int w = t >> 6, lane = t & 63;
  const int lm = lane & 15, lq = lane >> 4;
  const float SCALE2 = 0.10411754645f;  // 192^-0.5 * log2(e)

  const unsigned short* qp = qb + (((size_t)b * S_ + (q0 << 7) + (w << 4) + lm) * NH_ + h) * QHD_;
  bf16x8 qf[6];
#pragma unroll
  for (int s = 0; s < 6; ++s) qf[s] = *(const bf16x8*)(qp + s * 32 + (lq << 3));

  const floatx4 vzero = {0.f, 0.f, 0.f, 0.f};
  floatx4 of[8];
#pragma unroll
  for (int i = 0; i < 8; ++i) of[i] = vzero;
  float mrow[4] = {-1e30f, -1e30f, -1e30f, -1e30f};
  float lrow[4] = {0.f, 0.f, 0.f, 0.f};

  const unsigned short* kvbase = kvb + (size_t)(b * NH_ + h) * S_ * 256;
  const unsigned short* kpbase = kpe + (size_t)b * S_ * 64;

  // ---- prefetch state: 5 named uint4 (no arrays -> no scratch) ----
  uint4 rKa0, rKa1, rKp0, rVa0, rVb0;

  const int tK  = (t >> 4) * 256 + ((t & 15) << 3);   // K rows 0..31, chunk t&15
  const int tKp = (t >> 3) * 64 + ((t & 7) << 3);     // kpe rows 0..63
  const int cg  = t & 15;                              // V col-group
  const int kp  = t >> 4;                              // V row-pair 0..31
  const int tV  = (kp << 1) * 256 + 128 + (cg << 3);

#define LOAD_TILE(KT) do { \
    const unsigned short* kvt_ = kvbase + (size_t)((KT) << 6) * 256; \
    const unsigned short* kpt_ = kpbase + (size_t)((KT) << 6) * 64;  \
    rKa0 = *(const uint4*)(kvt_ + tK);                                \
    rKa1 = *(const uint4*)(kvt_ + 32 * 256 + tK);                     \
    rKp0 = *(const uint4*)(kpt_ + tKp);                               \
    rVa0 = *(const uint4*)(kvt_ + tV);                                \
    rVb0 = *(const uint4*)(kvt_ + tV + 256);                          \
  } while (0)

  LOAD_TILE(0);

  const int wKs  = (t >> 4) * 200 + ((t & 15) << 3);        // K dest rows 0..31
  const int wKps = (t >> 3) * 200 + 128 + ((t & 7) << 3);   // kpe dest
  const int scv  = (kp ^ ((cg & 7) << 2)) << 1;             // swizzled V col
  unsigned short* vbp = &Vt[(cg << 3) * 72 + scv];

  const int ktmax = (q0 << 1) + 1;
  const int qrel0 = (q0 << 7) + (w << 4);   // wave's first q-row

  for (int kt = 0; kt <= ktmax; ++kt) {
    __syncthreads();
    // ---- regs -> LDS (only LDS-write latency between the barriers) ----
    *(uint4*)&Ks[wKs]            = rKa0;
    *(uint4*)&Ks[32 * 200 + wKs] = rKa1;
    *(uint4*)&Ks[wKps]           = rKp0;
    *(unsigned int*)(vbp + 0 * 72) = (rVa0.x & 0xffffu) | (rVb0.x << 16);
    *(unsigned int*)(vbp + 1 * 72) = (rVa0.x >> 16)     | (rVb0.x & 0xffff0000u);
    *(unsigned int*)(vbp + 2 * 72) = (rVa0.y & 0xffffu) | (rVb0.y << 16);
    *(unsigned int*)(vbp + 3 * 72) = (rVa0.y >> 16)     | (rVb0.y & 0xffff0000u);
    *(unsigned int*)(vbp + 4 * 72) = (rVa0.z & 0xffffu) | (rVb0.z << 16);
    *(unsigned int*)(vbp + 5 * 72) = (rVa0.z >> 16)     | (rVb0.z & 0xffff0000u);
    *(unsigned int*)(vbp + 6 * 72) = (rVa0.w & 0xffffu) | (rVb0.w << 16);
    *(unsigned int*)(vbp + 7 * 72) = (rVa0.w >> 16)     | (rVb0.w & 0xffff0000u);
    __syncthreads();
    // ---- issue next tile's global loads; they drain under compute ----
    if (kt < ktmax) LOAD_TILE(kt + 1);

    const int rel = qrel0 - (kt << 6);   // wave-uniform
    if (rel >= 0) {
      const int nimax = (rel >= 64) ? 3 : (rel >> 4);

      floatx4 s0v = vzero, s1v = vzero, s2v = vzero, s3v = vzero;
      __builtin_amdgcn_s_setprio(1);
#define QKNI(SACC, NI) do { \
      _Pragma("unroll") \
      for (int s = 0; s < 6; ++s) { \
        const bf16x8 kf = *(const bf16x8*)&Ks[((NI) * 16 + lm) * 200 + s * 32 + (lq << 3)]; \
        SACC = __builtin_amdgcn_mfma_f32_16x16x32_bf16(qf[s], kf, SACC, 0, 0, 0); \
      } } while (0)
      QKNI(s0v, 0);
      if (nimax >= 1) QKNI(s1v, 1);
      if (nimax >= 2) QKNI(s2v, 2);
      if (nimax >= 3) QKNI(s3v, 3);
#undef QKNI
      __builtin_amdgcn_s_setprio(0);

      const bool dg = (rel < 64);
#pragma unroll
      for (int r = 0; r < 4; ++r) {
        const int rq = (lq << 2) + r;
        float a0 = s0v[r] * SCALE2;
        float a1 = s1v[r] * SCALE2;
        float a2 = s2v[r] * SCALE2;
        float a3 = s3v[r] * SCALE2;
        if (nimax < 1) a1 = -1e30f;
        if (nimax < 2) a2 = -1e30f;
        if (nimax < 3) a3 = -1e30f;
        if (dg) {
          const bool m = lm > rq;
          if (nimax == 0 && m) a0 = -1e30f;
          if (nimax == 1 && m) a1 = -1e30f;
          if (nimax == 2 && m) a2 = -1e30f;
          if (nimax == 3 && m) a3 = -1e30f;
        }
        float mx = fmaxf(fmaxf(a0, a1), fmaxf(a2, a3));
        mx = rmax16(mx);   // DPP allreduce over the 16-lane row
        // T13 defer-max: only rescale when the max moved by >6 (P <= 2^6)
        if (!__all(mx <= mrow[r] + 6.0f)) {
          const float mnew = fmaxf(mrow[r], mx);
          const float al = __builtin_amdgcn_exp2f(mrow[r] - mnew);
          mrow[r] = mnew;
          lrow[r] *= al;
#pragma unroll
          for (int vt = 0; vt < 8; ++vt) of[vt][r] *= al;
        }
        const float p0 = __builtin_amdgcn_exp2f(a0 - mrow[r]);
        const float p1 = __builtin_amdgcn_exp2f(a1 - mrow[r]);
        const float p2 = __builtin_amdgcn_exp2f(a2 - mrow[r]);
        const float p3 = __builtin_amdgcn_exp2f(a3 - mrow[r]);
        unsigned short* pr = &Ps[(w * 16 + rq) * 68 + lm];
        pr[0]  = f2bf(p0);
        pr[16] = f2bf(p1);
        pr[32] = f2bf(p2);
        pr[48] = f2bf(p3);
        float ps = (p0 + p1) + (p2 + p3);
        ps = rsum16(ps);   // DPP allreduce
        lrow[r] += ps;
      }

      // PV: ks2 = 0 always; ks2 = 1 iff rel >= 32
      __builtin_amdgcn_s_setprio(1);
      {
        const bf16x8 pf = *(const bf16x8*)&Ps[(w * 16 + lm) * 68 + (lq << 3)];
#pragma unroll
        for (int vt = 0; vt < 8; ++vt) {
          const int rr = vt * 16 + lm;
          const int c0 = (lq << 2);
          const bf16x8 vf = *(const bf16x8*)&Vt[rr * 72 + ((c0 ^ (((rr >> 3) & 7) << 2)) << 1)];
          of[vt] = __builtin_amdgcn_mfma_f32_16x16x32_bf16(pf, vf, of[vt], 0, 0, 0);
        }
      }
      if (rel >= 32) {
        const bf16x8 pf = *(const bf16x8*)&Ps[(w * 16 + lm) * 68 + 32 + (lq << 3)];
#pragma unroll
        for (int vt = 0; vt < 8; ++vt) {
          const int rr = vt * 16 + lm;
          const int c0 = 16 + (lq << 2);
          const bf16x8 vf = *(const bf16x8*)&Vt[rr * 72 + ((c0 ^ (((rr >> 3) & 7) << 2)) << 1)];
          of[vt] = __builtin_amdgcn_mfma_f32_16x16x32_bf16(pf, vf, of[vt], 0, 0, 0);
        }
      }
      __builtin_amdgcn_s_setprio(0);
    }
  }

#pragma unroll
  for (int r = 0; r < 4; ++r) {
    const int qrow = (q0 << 7) + (w << 4) + (lq << 2) + r;
    const float inv = 1.f / lrow[r];
    unsigned short* orow = o + ((size_t)b * S_ + qrow) * 4096 + h * 128;
#pragma unroll
    for (int vt = 0; vt < 8; ++vt)
      orow[vt * 16 + lm] = f2bf(of[vt][r] * inv);
  }
#undef LOAD_TILE
}

// ---------------------------------------------------------------------------
extern "C" void kernel_launch(void* const* d_in, const int* in_sizes, int n_in,
                              void* d_out, int out_size, void* d_ws, size_t ws_size,
                              hipStream_t stream) {
  (void)in_sizes; (void)n_in; (void)out_size; (void)ws_size;
  const float* hs   = (const float*)d_in[0];
  const float* cosp = (const float*)d_in[1];
  const float* sinp = (const float*)d_in[2];
  const int*   pos  = (const int*)d_in[3];
  const float* Wqa  = (const float*)d_in[4];
  const float* gqa  = (const float*)d_in[5];
  const float* bqa  = (const float*)d_in[6];
  const float* Wqb  = (const float*)d_in[7];
  const float* Wkva = (const float*)d_in[8];
  const float* gkva = (const float*)d_in[9];
  const float* bkva = (const float*)d_in[10];
  const float* Wkvb = (const float*)d_in[11];
  const float* Wo   = (const float*)d_in[12];
  float* out = (float*)d_out;

  char* ws = (char*)d_ws;
  // lifetime-aliased workspace (~204.5 MiB total)
  unsigned short* hsb   = (unsigned short*)(ws);               // 33,554,432
  float*          q_a   = (float*)(ws + 33554432);             // 25,165,824
  unsigned short* qb    = (unsigned short*)(ws);               // alias over hsb+q_a (50,331,648 <= 58,720,256)
  unsigned short* WqaT  = (unsigned short*)(ws + 58720256);    // 12,582,912 (1536x4096)
  unsigned short* WkvaT = (unsigned short*)(ws + 71303168);    //  5,242,880 (640x4096, rows 576+ poison; contiguous after WqaT)
  unsigned short* qln   = (unsigned short*)(ws + 58720256);    // alias over WqaT (12,582,912)
  unsigned short* kvln  = (unsigned short*)(ws + 71303168);    // alias over WkvaT (4,194,304)
  unsigned short* WqbT  = (unsigned short*)(ws + 76546048);    // 18,874,368 (6144x1536)
  float*          ckv   = (float*)(ws + 95420416);             //  9,437,184
  unsigned short* WkvbT = (unsigned short*)(ws + 104857600);   //  8,388,608 (8192x512)
  unsigned short* ob    = (unsigned short*)(ws + 76546048);    // alias over WqbT+ckv+WkvbT (33,554,432 <= 36,700,160)
  unsigned short* WoT   = (unsigned short*)(ws + 113246208);   // 33,554,432 (4096x4096)
  unsigned short* kvb   = (unsigned short*)(ws + 146800640);   // 67,108,864 (B,NH,S,256)
  unsigned short* kpe   = (unsigned short*)(ws + 213909504);   //    524,288

  const dim3 blk(256);
  // prepass: bf16 convert + weight transposes
  convert_kernel<<<dim3(8192), blk, 0, stream>>>(hs, hsb);
  transpose_kernel<<<dim3(48, 128), blk, 0, stream>>>(Wqa, WqaT, 4096, 1536);
  transpose_kernel<<<dim3(18, 128), blk, 0, stream>>>(Wkva, WkvaT, 4096, 576);
  transpose_kernel<<<dim3(192, 48), blk, 0, stream>>>(Wqb, WqbT, 1536, 6144);
  transpose_kernel<<<dim3(256, 16), blk, 0, stream>>>(Wkvb, WkvbT, 512, 8192);
  transpose_kernel<<<dim3(128, 128), blk, 0, stream>>>(Wo, WoT, 4096, 4096);

  // merged: q_a = hs @ Wqa AND ckv = hs @ Wkva in one launch (Bt rows
  // 0..1535 = WqaT, 1536..2111 = WkvaT; contiguous, same lda/ldb).
  gemm_bt<3><<<dim3(32, 17), blk, 0, stream>>>(hsb, WqaT, q_a, ckv, 2112, 4096, 4096, 4096, 0);
  // LN -> bf16 (qln over WqaT, kvln over WkvaT — both weights dead now)
  ln_kernel<<<dim3(4096), blk, 0, stream>>>(q_a, gqa, bqa, qln, 1536, 1536, 1536);
  ln_kernel<<<dim3(4096), blk, 0, stream>>>(ckv, gkva, bkva, kvln, 512, 576, 512);
  rope_k_kernel<<<dim3(512), blk, 0, stream>>>(ckv, cosp, sinp, pos, kpe);
  // qb = qln @ Wqb (qb over hsb+q_a — both dead now)
  gemm_bt<1><<<dim3(32, 48), blk, 0, stream>>>(qln, WqbT, qb, nullptr, 6144, 1536, 1536, 1536, 6144);
  rope_q_kernel<<<dim3(16384), blk, 0, stream>>>(qb, cosp, sinp, pos);
  // kvb = kvln @ Wkvb, scattered to (B,NH,S,256)
  gemm_bt<2><<<dim3(32, 64), blk, 0, stream>>>(kvln, WkvbT, kvb, nullptr, 8192, 512, 512, 512, 8192);
  // attention (ob over WqbT+ckv+WkvbT — all dead now)
  attn_kernel<<<dim3(8, 32, 4), dim3(512), 0, stream>>>(qb, kvb, kpe, ob);
  // out = ob @ Wo
  gemm_bt<0><<<dim3(32, 32), blk, 0, stream>>>(ob, WoT, out, nullptr, 4096, 4096, 4096, 4096, 4096);
}

// Round 6
// 862.322 us; speedup vs baseline: 1.6143x; 1.6143x over previous
//
#include <hip/hip_runtime.h>

// MLA shapes (fixed)
#define B_ 4
#define S_ 1024
#define H_ 4096
#define NH_ 32
#define QHD_ 192
#define EPS_ 1e-6f

typedef __bf16 bf16x8 __attribute__((ext_vector_type(8)));
typedef float floatx4 __attribute__((ext_vector_type(4)));

__device__ __forceinline__ unsigned short f2bf(float f) {
  unsigned int u = __builtin_bit_cast(unsigned int, f);
  u += 0x7fffu + ((u >> 16) & 1u);   // round-to-nearest-even (finite data only)
  return (unsigned short)(u >> 16);
}
__device__ __forceinline__ float bf2f(unsigned short s) {
  return __builtin_bit_cast(float, ((unsigned int)s) << 16);
}

// async global->LDS, 16B per lane; LDS dest = wave-uniform base + lane*16 (m104)
__device__ __forceinline__ void gload16(const unsigned short* g, unsigned short* l) {
  __builtin_amdgcn_global_load_lds(
      (const __attribute__((address_space(1))) void*)g,
      (__attribute__((address_space(3))) void*)l, 16, 0, 0);
}

// DPP row_ror cross-lane (VALU pipe, per-16-lane row = our lm groups).
template<int C>
__device__ __forceinline__ float dpp_ror(float v) {
  return __builtin_bit_cast(float,
      __builtin_amdgcn_mov_dpp(__builtin_bit_cast(int, v), 0x120 | C, 0xf, 0xf, false));
}
__device__ __forceinline__ float rmax16(float v) {   // allreduce max over 16-lane row
  v = fmaxf(v, dpp_ror<1>(v));
  v = fmaxf(v, dpp_ror<2>(v));
  v = fmaxf(v, dpp_ror<4>(v));
  v = fmaxf(v, dpp_ror<8>(v));
  return v;
}
__device__ __forceinline__ float rsum16(float v) {   // allreduce sum over 16-lane row
  v += dpp_ror<1>(v);
  v += dpp_ror<2>(v);
  v += dpp_ror<4>(v);
  v += dpp_ror<8>(v);
  return v;
}

// ---------------------------------------------------------------------------
// fp32 -> bf16 convert (hs), 8 elems/thread
// ---------------------------------------------------------------------------
__global__ __launch_bounds__(256) void convert_kernel(
    const float* __restrict__ x, unsigned short* __restrict__ y)
{
  const int i = (blockIdx.x * 256 + threadIdx.x) * 8;
  const float4 a = *(const float4*)(x + i);
  const float4 b = *(const float4*)(x + i + 4);
  ushort4 u, v;
  u.x = f2bf(a.x); u.y = f2bf(a.y); u.z = f2bf(a.z); u.w = f2bf(a.w);
  v.x = f2bf(b.x); v.y = f2bf(b.y); v.z = f2bf(b.z); v.w = f2bf(b.w);
  *(ushort4*)(y + i) = u;
  *(ushort4*)(y + i + 4) = v;
}

// ---------------------------------------------------------------------------
// W (KxN fp32 row-major) -> Wt (NxK bf16 row-major). 32x32 LDS tiles.
// ---------------------------------------------------------------------------
__global__ __launch_bounds__(256) void transpose_kernel(
    const float* __restrict__ W, unsigned short* __restrict__ Wt,
    const int K, const int N)
{
  __shared__ float tile[32][33];
  const int tx = threadIdx.x & 31, ty = threadIdx.x >> 5;
  const int nb = blockIdx.x << 5, kb = blockIdx.y << 5;
#pragma unroll
  for (int j = 0; j < 4; ++j)
    tile[ty + j * 8][tx] = W[(size_t)(kb + ty + j * 8) * N + nb + tx];
  __syncthreads();
#pragma unroll
  for (int j = 0; j < 4; ++j)
    Wt[(size_t)(nb + ty + j * 8) * K + kb + tx] = f2bf(tile[tx][ty + j * 8]);
}

// ---------------------------------------------------------------------------
// m97-class GEMM: C(MxN) = A(MxK) @ Bt(NxK)^T, both bf16, staged via
// global_load_lds width=16 into unpadded LDS [128][32]. 128x128 tile, BK=32,
// 4 waves (2x2 of 64x64), mfma_f32_16x16x32_bf16.
// OMODE: 0 = fp32 row-major; 1 = bf16 row-major; 2 = bf16 (B,NH,S,256) kv;
//        3 = split fp32: col<1536 -> Cv (ldc 1536), else Cv2 (ldc 576).
// M%128==0, K%32==0; Bt rows padded to 128-mult (pad contents finite poison).
// ---------------------------------------------------------------------------
template<int OMODE>
__global__ __launch_bounds__(256, 2) void gemm_bt(
    const unsigned short* __restrict__ A, const unsigned short* __restrict__ Bt,
    void* __restrict__ Cv, void* __restrict__ Cv2, const int N, const int K,
    const int lda, const int ldb, const int ldc)
{
  __shared__ unsigned short As[128 * 32];
  __shared__ unsigned short Bs[128 * 32];

  const int t = threadIdx.x;
  const int m0 = blockIdx.x * 128, n0 = blockIdx.y * 128;
  const int w = t >> 6, lane = t & 63;
  const int wm = (w >> 1) << 6, wn = (w & 1) << 6;
  const int lm = lane & 15, lq = lane >> 4;

  const floatx4 vzero = {0.f, 0.f, 0.f, 0.f};
  floatx4 acc[4][4];
#pragma unroll
  for (int i = 0; i < 4; ++i)
#pragma unroll
    for (int j = 0; j < 4; ++j) acc[i][j] = vzero;

  // staging: wave w does calls i=0,1; call covers 16 rows x 32 cols (1 KB).
  const int srow = (w << 5) + (lane >> 2);
  const int skc = (lane & 3) << 3;
  const unsigned short* gA = A + (size_t)(m0 + srow) * lda + skc;
  const unsigned short* gB = Bt + (size_t)(n0 + srow) * ldb + skc;
  unsigned short* lA0 = &As[(w << 1) * 512];
  unsigned short* lA1 = &As[((w << 1) + 1) * 512];
  unsigned short* lB0 = &Bs[(w << 1) * 512];
  unsigned short* lB1 = &Bs[((w << 1) + 1) * 512];

  const int nk = K >> 5;
  for (int kb = 0; kb < nk; ++kb) {
    const int k0 = kb << 5;
    __syncthreads();
    gload16(gA + k0, lA0);
    gload16(gA + (size_t)16 * lda + k0, lA1);
    gload16(gB + k0, lB0);
    gload16(gB + (size_t)16 * ldb + k0, lB1);
    __syncthreads();

    bf16x8 af[4], bfr[4];
#pragma unroll
    for (int mi = 0; mi < 4; ++mi)
      af[mi] = *(const bf16x8*)&As[(wm + mi * 16 + lm) * 32 + (lq << 3)];
#pragma unroll
    for (int ni = 0; ni < 4; ++ni)
      bfr[ni] = *(const bf16x8*)&Bs[(wn + ni * 16 + lm) * 32 + (lq << 3)];
#pragma unroll
    for (int mi = 0; mi < 4; ++mi)
#pragma unroll
      for (int ni = 0; ni < 4; ++ni)
        acc[mi][ni] = __builtin_amdgcn_mfma_f32_16x16x32_bf16(af[mi], bfr[ni], acc[mi][ni], 0, 0, 0);
  }

#pragma unroll
  for (int mi = 0; mi < 4; ++mi) {
    const int row = m0 + wm + mi * 16 + (lq << 2);
#pragma unroll
    for (int ni = 0; ni < 4; ++ni) {
      const int col = n0 + wn + ni * 16 + lm;
      if (col < N) {
#pragma unroll
        for (int r = 0; r < 4; ++r) {
          if constexpr (OMODE == 0)
            ((float*)Cv)[(size_t)(row + r) * ldc + col] = acc[mi][ni][r];
          else if constexpr (OMODE == 1)
            ((unsigned short*)Cv)[(size_t)(row + r) * ldc + col] = f2bf(acc[mi][ni][r]);
          else if constexpr (OMODE == 2) {
            const int rr2 = row + r;  // (B,NH,S,256): h=col>>8, d=col&255
            ((unsigned short*)Cv)[(((size_t)(rr2 >> 10) * NH_ + (col >> 8)) * S_ + (rr2 & 1023)) * 256 + (col & 255)] = f2bf(acc[mi][ni][r]);
          } else {  // OMODE == 3: q_a (cols 0..1535) | ckv (cols 1536..2111)
            if (col < 1536)
              ((float*)Cv)[(size_t)(row + r) * 1536 + col] = acc[mi][ni][r];
            else
              ((float*)Cv2)[(size_t)(row + r) * 576 + (col - 1536)] = acc[mi][ni][r];
          }
        }
      }
    }
  }
}

// ---------------------------------------------------------------------------
// LayerNorm: x fp32 rows (len L, stride xstride) -> y bf16 (stride ystride).
// ---------------------------------------------------------------------------
__global__ __launch_bounds__(256) void ln_kernel(
    const float* __restrict__ x, const float* __restrict__ g,
    const float* __restrict__ bias, unsigned short* __restrict__ y,
    const int L, const int xstride, const int ystride)
{
  __shared__ float sh[4];
  const int t = threadIdx.x;
  const float* xr = x + (size_t)blockIdx.x * xstride;
  unsigned short* yr = y + (size_t)blockIdx.x * ystride;
  const int n = L >> 8;
  float vals[6];
  float s = 0.f;
  for (int i = 0; i < n; ++i) { vals[i] = xr[t + (i << 8)]; s += vals[i]; }
#pragma unroll
  for (int off = 32; off; off >>= 1) s += __shfl_down(s, off);
  if ((t & 63) == 0) sh[t >> 6] = s;
  __syncthreads();
  const float mean = (sh[0] + sh[1] + sh[2] + sh[3]) / (float)L;
  float vs = 0.f;
  for (int i = 0; i < n; ++i) { const float d = vals[i] - mean; vs += d * d; }
#pragma unroll
  for (int off = 32; off; off >>= 1) vs += __shfl_down(vs, off);
  __syncthreads();
  if ((t & 63) == 0) sh[t >> 6] = vs;
  __syncthreads();
  const float inv = rsqrtf((sh[0] + sh[1] + sh[2] + sh[3]) / (float)L + EPS_);
  for (int i = 0; i < n; ++i) {
    const int c = t + (i << 8);
    yr[c] = f2bf((vals[i] - mean) * inv * g[c] + bias[c]);
  }
}

// ---------------------------------------------------------------------------
// RoPE on q_pe (cols 128..191 of each 192-wide head), in place on bf16 q.
// ---------------------------------------------------------------------------
__global__ __launch_bounds__(256) void rope_q_kernel(
    unsigned short* __restrict__ q, const float* __restrict__ cosp,
    const float* __restrict__ sinp, const int* __restrict__ pos)
{
  const int i = blockIdx.x * 256 + threadIdx.x;  // B*S*NH*32
  const int p = i & 31;
  const int h = (i >> 5) & 31;
  const int bs = i >> 10;
  const int pid = pos[bs];
  const size_t base = ((size_t)bs * NH_ + h) * QHD_ + 128;
  const float x1 = bf2f(q[base + p]);
  const float x2 = bf2f(q[base + p + 32]);
  const float* cr = cosp + (size_t)pid * 64;
  const float* sr = sinp + (size_t)pid * 64;
  q[base + p]      = f2bf(x1 * cr[p] - x2 * sr[p]);
  q[base + p + 32] = f2bf(x2 * cr[p + 32] + x1 * sr[p + 32]);
}

// RoPE on k_pe: ckv cols 512..575 (fp32) -> kpe bf16 (B,S,64)
__global__ __launch_bounds__(256) void rope_k_kernel(
    const float* __restrict__ ckv, const float* __restrict__ cosp,
    const float* __restrict__ sinp, const int* __restrict__ pos,
    unsigned short* __restrict__ kpe)
{
  const int i = blockIdx.x * 256 + threadIdx.x;  // B*S*32
  const int p = i & 31;
  const int bs = i >> 5;
  const int pid = pos[bs];
  const float* row = ckv + (size_t)bs * 576 + 512;
  const float x1 = row[p], x2 = row[p + 32];
  const float* cr = cosp + (size_t)pid * 64;
  const float* sr = sinp + (size_t)pid * 64;
  kpe[(size_t)bs * 64 + p]      = f2bf(x1 * cr[p] - x2 * sr[p]);
  kpe[(size_t)bs * 64 + p + 32] = f2bf(x2 * cr[p + 32] + x1 * sr[p + 32]);
}

// ---------------------------------------------------------------------------
// MFMA flash attention. Block = 8 waves = (b,h,128 q). Round-6 changes:
//  (a) __launch_bounds__(512, 2): LDS (62464B) caps at 2 blocks/CU = 4
//      waves/SIMD regardless, so allow the full 256-VGPR budget. Round 5's
//      allocator pinned 64 VGPR (8-wave heuristic) and spilled of[8] every
//      tile (~1GB scratch traffic, attn 244->728us). This un-spills with
//      zero occupancy cost.
//  (b) Ps stride back to 72 (144B rows: 16B-aligned so PV loads stay
//      ds_read_b128; store conflicts are only 2-way = free per m136.
//      Round 5's stride-68 "fix" broke alignment for no gain).
//  (c) kept: DPP row_ror softmax reduces (VALU pipe), T13 defer-max THR=6,
//      s_setprio around MFMA, merged qa+kva GEMM, named-reg T14 prefetch,
//      static-index compute, Vt XOR-swizzle, base-2 softmax.
// ---------------------------------------------------------------------------
__global__ __launch_bounds__(512, 2) void attn_kernel(
    const unsigned short* __restrict__ qb, const unsigned short* __restrict__ kvb,
    const unsigned short* __restrict__ kpe, unsigned short* __restrict__ o)
{
  __shared__ unsigned short Ks[64 * 200];      // [k][d 0..191], stride 200
  __shared__ unsigned short Vt[128 * 72];      // [vd][k], stride 72, swizzled cols
  __shared__ unsigned short Ps[8 * 16 * 72];   // per-wave [m][k], stride 72

  const int t = threadIdx.x;
  const int q0 = (int)gridDim.x - 1 - (int)blockIdx.x;  // longest first
  const int h = blockIdx.y, b = blockIdx.z;
  const int w = t >> 6, lane = t & 63;
  const int lm = lane & 15, lq = lane >> 4;
  const float SCALE2 = 0.10411754645f;  // 192^-0.5 * log2(e)

  const unsigned short* qp = qb + (((size_t)b * S_ + (q0 << 7) + (w << 4) + lm) * NH_ + h) * QHD_;
  bf16x8 qf[6];
#pragma unroll
  for (int s = 0; s < 6; ++s) qf[s] = *(const bf16x8*)(qp + s * 32 + (lq << 3));

  const floatx4 vzero = {0.f, 0.f, 0.f, 0.f};
  floatx4 of[8];
#pragma unroll
  for (int i = 0; i < 8; ++i) of[i] = vzero;
  float mrow[4] = {-1e30f, -1e30f, -1e30f, -1e30f};
  float lrow[4] = {0.f, 0.f, 0.f, 0.f};

  const unsigned short* kvbase = kvb + (size_t)(b * NH_ + h) * S_ * 256;
  const unsigned short* kpbase = kpe + (size_t)b * S_ * 64;

  // ---- prefetch state: 5 named uint4 (no arrays -> no scratch) ----
  uint4 rKa0, rKa1, rKp0, rVa0, rVb0;

  const int tK  = (t >> 4) * 256 + ((t & 15) << 3);   // K rows 0..31, chunk t&15
  const int tKp = (t >> 3) * 64 + ((t & 7) << 3);     // kpe rows 0..63
  const int cg  = t & 15;                              // V col-group
  const int kp  = t >> 4;                              // V row-pair 0..31
  const int tV  = (kp << 1) * 256 + 128 + (cg << 3);

#define LOAD_TILE(KT) do { \
    const unsigned short* kvt_ = kvbase + (size_t)((KT) << 6) * 256; \
    const unsigned short* kpt_ = kpbase + (size_t)((KT) << 6) * 64;  \
    rKa0 = *(const uint4*)(kvt_ + tK);                                \
    rKa1 = *(const uint4*)(kvt_ + 32 * 256 + tK);                     \
    rKp0 = *(const uint4*)(kpt_ + tKp);                               \
    rVa0 = *(const uint4*)(kvt_ + tV);                                \
    rVb0 = *(const uint4*)(kvt_ + tV + 256);                          \
  } while (0)

  LOAD_TILE(0);

  const int wKs  = (t >> 4) * 200 + ((t & 15) << 3);        // K dest rows 0..31
  const int wKps = (t >> 3) * 200 + 128 + ((t & 7) << 3);   // kpe dest
  const int scv  = (kp ^ ((cg & 7) << 2)) << 1;             // swizzled V col
  unsigned short* vbp = &Vt[(cg << 3) * 72 + scv];

  const int ktmax = (q0 << 1) + 1;
  const int qrel0 = (q0 << 7) + (w << 4);   // wave's first q-row

  for (int kt = 0; kt <= ktmax; ++kt) {
    __syncthreads();
    // ---- regs -> LDS (only LDS-write latency between the barriers) ----
    *(uint4*)&Ks[wKs]            = rKa0;
    *(uint4*)&Ks[32 * 200 + wKs] = rKa1;
    *(uint4*)&Ks[wKps]           = rKp0;
    *(unsigned int*)(vbp + 0 * 72) = (rVa0.x & 0xffffu) | (rVb0.x << 16);
    *(unsigned int*)(vbp + 1 * 72) = (rVa0.x >> 16)     | (rVb0.x & 0xffff0000u);
    *(unsigned int*)(vbp + 2 * 72) = (rVa0.y & 0xffffu) | (rVb0.y << 16);
    *(unsigned int*)(vbp + 3 * 72) = (rVa0.y >> 16)     | (rVb0.y & 0xffff0000u);
    *(unsigned int*)(vbp + 4 * 72) = (rVa0.z & 0xffffu) | (rVb0.z << 16);
    *(unsigned int*)(vbp + 5 * 72) = (rVa0.z >> 16)     | (rVb0.z & 0xffff0000u);
    *(unsigned int*)(vbp + 6 * 72) = (rVa0.w & 0xffffu) | (rVb0.w << 16);
    *(unsigned int*)(vbp + 7 * 72) = (rVa0.w >> 16)     | (rVb0.w & 0xffff0000u);
    __syncthreads();
    // ---- issue next tile's global loads; they drain under compute ----
    if (kt < ktmax) LOAD_TILE(kt + 1);

    const int rel = qrel0 - (kt << 6);   // wave-uniform
    if (rel >= 0) {
      const int nimax = (rel >= 64) ? 3 : (rel >> 4);

      floatx4 s0v = vzero, s1v = vzero, s2v = vzero, s3v = vzero;
      __builtin_amdgcn_s_setprio(1);
#define QKNI(SACC, NI) do { \
      _Pragma("unroll") \
      for (int s = 0; s < 6; ++s) { \
        const bf16x8 kf = *(const bf16x8*)&Ks[((NI) * 16 + lm) * 200 + s * 32 + (lq << 3)]; \
        SACC = __builtin_amdgcn_mfma_f32_16x16x32_bf16(qf[s], kf, SACC, 0, 0, 0); \
      } } while (0)
      QKNI(s0v, 0);
      if (nimax >= 1) QKNI(s1v, 1);
      if (nimax >= 2) QKNI(s2v, 2);
      if (nimax >= 3) QKNI(s3v, 3);
#undef QKNI
      __builtin_amdgcn_s_setprio(0);

      const bool dg = (rel < 64);
#pragma unroll
      for (int r = 0; r < 4; ++r) {
        const int rq = (lq << 2) + r;
        float a0 = s0v[r] * SCALE2;
        float a1 = s1v[r] * SCALE2;
        float a2 = s2v[r] * SCALE2;
        float a3 = s3v[r] * SCALE2;
        if (nimax < 1) a1 = -1e30f;
        if (nimax < 2) a2 = -1e30f;
        if (nimax < 3) a3 = -1e30f;
        if (dg) {
          const bool m = lm > rq;
          if (nimax == 0 && m) a0 = -1e30f;
          if (nimax == 1 && m) a1 = -1e30f;
          if (nimax == 2 && m) a2 = -1e30f;
          if (nimax == 3 && m) a3 = -1e30f;
        }
        float mx = fmaxf(fmaxf(a0, a1), fmaxf(a2, a3));
        mx = rmax16(mx);   // DPP allreduce over the 16-lane row
        // T13 defer-max: only rescale when the max moved by >6 (P <= 2^6)
        if (!__all(mx <= mrow[r] + 6.0f)) {
          const float mnew = fmaxf(mrow[r], mx);
          const float al = __builtin_amdgcn_exp2f(mrow[r] - mnew);
          mrow[r] = mnew;
          lrow[r] *= al;
#pragma unroll
          for (int vt = 0; vt < 8; ++vt) of[vt][r] *= al;
        }
        const float p0 = __builtin_amdgcn_exp2f(a0 - mrow[r]);
        const float p1 = __builtin_amdgcn_exp2f(a1 - mrow[r]);
        const float p2 = __builtin_amdgcn_exp2f(a2 - mrow[r]);
        const float p3 = __builtin_amdgcn_exp2f(a3 - mrow[r]);
        unsigned short* pr = &Ps[(w * 16 + rq) * 72 + lm];
        pr[0]  = f2bf(p0);
        pr[16] = f2bf(p1);
        pr[32] = f2bf(p2);
        pr[48] = f2bf(p3);
        float ps = (p0 + p1) + (p2 + p3);
        ps = rsum16(ps);   // DPP allreduce
        lrow[r] += ps;
      }

      // PV: ks2 = 0 always; ks2 = 1 iff rel >= 32
      __builtin_amdgcn_s_setprio(1);
      {
        const bf16x8 pf = *(const bf16x8*)&Ps[(w * 16 + lm) * 72 + (lq << 3)];
#pragma unroll
        for (int vt = 0; vt < 8; ++vt) {
          const int rr = vt * 16 + lm;
          const int c0 = (lq << 2);
          const bf16x8 vf = *(const bf16x8*)&Vt[rr * 72 + ((c0 ^ (((rr >> 3) & 7) << 2)) << 1)];
          of[vt] = __builtin_amdgcn_mfma_f32_16x16x32_bf16(pf, vf, of[vt], 0, 0, 0);
        }
      }
      if (rel >= 32) {
        const bf16x8 pf = *(const bf16x8*)&Ps[(w * 16 + lm) * 72 + 32 + (lq << 3)];
#pragma unroll
        for (int vt = 0; vt < 8; ++vt) {
          const int rr = vt * 16 + lm;
          const int c0 = 16 + (lq << 2);
          const bf16x8 vf = *(const bf16x8*)&Vt[rr * 72 + ((c0 ^ (((rr >> 3) & 7) << 2)) << 1)];
          of[vt] = __builtin_amdgcn_mfma_f32_16x16x32_bf16(pf, vf, of[vt], 0, 0, 0);
        }
      }
      __builtin_amdgcn_s_setprio(0);
    }
  }

#pragma unroll
  for (int r = 0; r < 4; ++r) {
    const int qrow = (q0 << 7) + (w << 4) + (lq << 2) + r;
    const float inv = 1.f / lrow[r];
    unsigned short* orow = o + ((size_t)b * S_ + qrow) * 4096 + h * 128;
#pragma unroll
    for (int vt = 0; vt < 8; ++vt)
      orow[vt * 16 + lm] = f2bf(of[vt][r] * inv);
  }
#undef LOAD_TILE
}

// ---------------------------------------------------------------------------
extern "C" void kernel_launch(void* const* d_in, const int* in_sizes, int n_in,
                              void* d_out, int out_size, void* d_ws, size_t ws_size,
                              hipStream_t stream) {
  (void)in_sizes; (void)n_in; (void)out_size; (void)ws_size;
  const float* hs   = (const float*)d_in[0];
  const float* cosp = (const float*)d_in[1];
  const float* sinp = (const float*)d_in[2];
  const int*   pos  = (const int*)d_in[3];
  const float* Wqa  = (const float*)d_in[4];
  const float* gqa  = (const float*)d_in[5];
  const float* bqa  = (const float*)d_in[6];
  const float* Wqb  = (const float*)d_in[7];
  const float* Wkva = (const float*)d_in[8];
  const float* gkva = (const float*)d_in[9];
  const float* bkva = (const float*)d_in[10];
  const float* Wkvb = (const float*)d_in[11];
  const float* Wo   = (const float*)d_in[12];
  float* out = (float*)d_out;

  char* ws = (char*)d_ws;
  // lifetime-aliased workspace (~204.5 MiB total)
  unsigned short* hsb   = (unsigned short*)(ws);               // 33,554,432
  float*          q_a   = (float*)(ws + 33554432);             // 25,165,824
  unsigned short* qb    = (unsigned short*)(ws);               // alias over hsb+q_a (50,331,648 <= 58,720,256)
  unsigned short* WqaT  = (unsigned short*)(ws + 58720256);    // 12,582,912 (1536x4096)
  unsigned short* WkvaT = (unsigned short*)(ws + 71303168);    //  5,242,880 (640x4096, rows 576+ poison; contiguous after WqaT)
  unsigned short* qln   = (unsigned short*)(ws + 58720256);    // alias over WqaT (12,582,912)
  unsigned short* kvln  = (unsigned short*)(ws + 71303168);    // alias over WkvaT (4,194,304)
  unsigned short* WqbT  = (unsigned short*)(ws + 76546048);    // 18,874,368 (6144x1536)
  float*          ckv   = (float*)(ws + 95420416);             //  9,437,184
  unsigned short* WkvbT = (unsigned short*)(ws + 104857600);   //  8,388,608 (8192x512)
  unsigned short* ob    = (unsigned short*)(ws + 76546048);    // alias over WqbT+ckv+WkvbT (33,554,432 <= 36,700,160)
  unsigned short* WoT   = (unsigned short*)(ws + 113246208);   // 33,554,432 (4096x4096)
  unsigned short* kvb   = (unsigned short*)(ws + 146800640);   // 67,108,864 (B,NH,S,256)
  unsigned short* kpe   = (unsigned short*)(ws + 213909504);   //    524,288

  const dim3 blk(256);
  // prepass: bf16 convert + weight transposes
  convert_kernel<<<dim3(8192), blk, 0, stream>>>(hs, hsb);
  transpose_kernel<<<dim3(48, 128), blk, 0, stream>>>(Wqa, WqaT, 4096, 1536);
  transpose_kernel<<<dim3(18, 128), blk, 0, stream>>>(Wkva, WkvaT, 4096, 576);
  transpose_kernel<<<dim3(192, 48), blk, 0, stream>>>(Wqb, WqbT, 1536, 6144);
  transpose_kernel<<<dim3(256, 16), blk, 0, stream>>>(Wkvb, WkvbT, 512, 8192);
  transpose_kernel<<<dim3(128, 128), blk, 0, stream>>>(Wo, WoT, 4096, 4096);

  // merged: q_a = hs @ Wqa AND ckv = hs @ Wkva in one launch (Bt rows
  // 0..1535 = WqaT, 1536..2111 = WkvaT; contiguous, same lda/ldb).
  gemm_bt<3><<<dim3(32, 17), blk, 0, stream>>>(hsb, WqaT, q_a, ckv, 2112, 4096, 4096, 4096, 0);
  // LN -> bf16 (qln over WqaT, kvln over WkvaT — both weights dead now)
  ln_kernel<<<dim3(4096), blk, 0, stream>>>(q_a, gqa, bqa, qln, 1536, 1536, 1536);
  ln_kernel<<<dim3(4096), blk, 0, stream>>>(ckv, gkva, bkva, kvln, 512, 576, 512);
  rope_k_kernel<<<dim3(512), blk, 0, stream>>>(ckv, cosp, sinp, pos, kpe);
  // qb = qln @ Wqb (qb over hsb+q_a — both dead now)
  gemm_bt<1><<<dim3(32, 48), blk, 0, stream>>>(qln, WqbT, qb, nullptr, 6144, 1536, 1536, 1536, 6144);
  rope_q_kernel<<<dim3(16384), blk, 0, stream>>>(qb, cosp, sinp, pos);
  // kvb = kvln @ Wkvb, scattered to (B,NH,S,256)
  gemm_bt<2><<<dim3(32, 64), blk, 0, stream>>>(kvln, WkvbT, kvb, nullptr, 8192, 512, 512, 512, 8192);
  // attention (ob over WqbT+ckv+WkvbT — all dead now)
  attn_kernel<<<dim3(8, 32, 4), dim3(512), 0, stream>>>(qb, kvb, kpe, ob);
  // out = ob @ Wo
  gemm_bt<0><<<dim3(32, 32), blk, 0, stream>>>(ob, WoT, out, nullptr, 4096, 4096, 4096, 4096, 4096);
}